// Round 3
// baseline (532.836 us; speedup 1.0000x reference)
//
#include <hip/hip_runtime.h>

// B=131072, T=16, D=2, H=64. 16 rows/wave, 4 waves/block, h-state in MFMA C-layout regs.
#define BSZ 131072
#define TT  16
#define RPB 64
#define BLK 256

typedef __bf16 bf16x8 __attribute__((ext_vector_type(8)));
typedef float  f32x4  __attribute__((ext_vector_type(4)));

#define MFMA(a,b,c) __builtin_amdgcn_mfma_f32_16x16x32_bf16((a),(b),(c),0,0,0)

static __device__ __forceinline__ float rcp_f(float v){ float r; asm("v_rcp_f32 %0, %1" : "=v"(r) : "v"(v)); return r; }
static __device__ __forceinline__ float sigm(float v){ return rcp_f(1.0f + __expf(-v)); }
static __device__ __forceinline__ float tanh_f(float v){ return 1.0f - 2.0f*rcp_f(1.0f + __expf(2.0f*v)); }

// launch_bounds(256,3): VGPR cap 170 -> Whh frags (96) + hst (16) + working set fit
// without rematerialization; 3 waves/SIMD = 12 waves/CU.
__global__ __launch_bounds__(BLK, 3) void flow3(
    const float* __restrict__ x,     // (B,16,2)
    const float* __restrict__ z,     // (B,64)
    const float* __restrict__ W_ih,  // (192,2)
    const float* __restrict__ W_hh,  // (192,64)
    const float* __restrict__ b_ih,  // (192)
    const float* __restrict__ b_hh,  // (192)
    const float* __restrict__ W1,    // (64,32)
    const float* __restrict__ b1,    // (32)
    const float* __restrict__ W2,    // (32,4)
    const float* __restrict__ b2,    // (4)
    float* __restrict__ y_out,       // (B,16,2)
    float* __restrict__ lad_out)     // (B)
{
  __shared__ __align__(16) __bf16 hbuf[RPB*72];     // h (bf16), A-frag layout, stride 72
  __shared__ __align__(16) __bf16 hidbuf[RPB*40];   // MLP hidden, stride 40
  __shared__ __align__(16) float4 gi_tab[192];      // {Wih0, Wih1, bias, 0} per GRU column
  __shared__ __align__(16) __bf16 w1tab[4*64*8];    // W1 B-frags, [frag][lane] layout
  __shared__ __align__(16) __bf16 w2tab[64*8];      // W2 B-frag
  __shared__ __align__(16) float  lsbuf[RPB*4];
  __shared__ __align__(16) float  ystate[RPB*2];    // y_{t-1}, [row][comp]
  __shared__ __align__(16) float  ybuf[RPB*34];     // y history, stride 34 (conflict-free)

  const int tid  = threadIdx.x;
  const int lane = tid & 63, wave = tid >> 6;
  const int quad = lane >> 4, n16 = lane & 15;
  const int gb   = blockIdx.x * RPB;
  const f32x4 zero = {0.f,0.f,0.f,0.f};

  // ---------- one-time staging ----------
  if (tid < 192) {  // gi_tab: n-gate bias = b_ih only (b_hh_n folded into cn C-init)
    const int j = tid;
    const float w0 = W_ih[2*j], w1 = W_ih[2*j+1];
    const float bi = b_ih[j], bh = b_hh[j];
    gi_tab[j] = make_float4(w0, w1, (j < 128) ? bi + bh : bi, 0.f);
  }
  { // w1tab: frag f = c2*2+kt, per-lane 16B
    const int f = tid >> 6, c2 = f >> 1, kt = f & 1;
    bf16x8 v;
    #pragma unroll
    for (int j = 0; j < 8; ++j)
      v[j] = (__bf16)W1[(size_t)(kt*32 + quad*8 + j)*32 + c2*16 + n16];
    *(bf16x8*)&w1tab[(f*64 + lane)*8] = v;
  }
  if (tid < 64) {
    bf16x8 v;
    #pragma unroll
    for (int j = 0; j < 8; ++j)
      v[j] = (n16 < 4) ? (__bf16)W2[(size_t)(quad*8 + j)*4 + n16] : (__bf16)0.f;
    *(bf16x8*)&w2tab[lane*8] = v;
  }
  if (tid < 128) ystate[tid] = 0.f;
  #pragma unroll
  for (int r4 = 0; r4 < 4; ++r4) {  // z -> hbuf (bf16)
    const int row = (tid >> 4) + r4*16, col = (tid & 15)*4;
    const float4 zv = *(const float4*)&z[(size_t)(gb + row)*64 + col];
    hbuf[row*72 + col+0] = (__bf16)zv.x; hbuf[row*72 + col+1] = (__bf16)zv.y;
    hbuf[row*72 + col+2] = (__bf16)zv.z; hbuf[row*72 + col+3] = (__bf16)zv.w;
  }

  // Whh B-frags in registers: 24 x bf16x8 = 96 VGPR. frag[ct][kt], ct = gate*4+g.
  bf16x8 Whh[12][2];
  #pragma unroll
  for (int ct = 0; ct < 12; ++ct)
    #pragma unroll
    for (int kt = 0; kt < 2; ++kt) {
      const float* p = W_hh + (size_t)(ct*16 + n16)*64 + kt*32 + quad*8;
      bf16x8 f;
      #pragma unroll
      for (int j = 0; j < 8; ++j) f[j] = (__bf16)p[j];
      Whh[ct][kt] = f;
    }
  // h in C-layout fp32 regs (exact carry): hst[g][i] = h[quad*4+i][g*16+n16]
  f32x4 hst[4];
  #pragma unroll
  for (int g = 0; g < 4; ++g)
    #pragma unroll
    for (int i = 0; i < 4; ++i)
      hst[g][i] = z[(size_t)(gb + wave*16 + quad*4 + i)*64 + g*16 + n16];
  // biases folded into C-inits
  float bhn[4];
  #pragma unroll
  for (int g = 0; g < 4; ++g) bhn[g] = b_hh[128 + g*16 + n16];
  const float b1v0 = b1[n16], b1v1 = b1[16 + n16];
  const float b2ln = (n16 < 4) ? b2[n16] : 0.f;

  __syncthreads();  // only barrier; all later LDS traffic is wave-private rows

  const int arow = wave*16 + n16;
  // A-frags of current h, loop-carried (re-read after gate writes, reused for MLP1 + next t)
  bf16x8 a0 = *(const bf16x8*)&hbuf[arow*72 + quad*8];
  bf16x8 a1 = *(const bf16x8*)&hbuf[arow*72 + 32 + quad*8];

  // epilogue lanes: 32 active, comp c = lane>>4, row = lane&15
  const int erow = wave*16 + (lane & 15);
  const int comp = (lane >> 4) & 1;
  const float* xp = x + (size_t)(gb + erow)*(TT*2) + comp;  // valid lanes<32
  float yc = 0.f, lad = 0.f;

  #pragma unroll 1
  for (int t = 0; t < TT; ++t) {
    // y_{t-1} per C-row (broadcast reads)
    float ys0[4], ys1[4];
    #pragma unroll
    for (int i = 0; i < 4; ++i) {
      ys0[i] = ystate[(wave*16 + quad*4 + i)*2];
      ys1[i] = ystate[(wave*16 + quad*4 + i)*2 + 1];
    }

    // ---- GRU per col-group g: 6 MFMA + elementwise gates ----
    #pragma unroll
    for (int g = 0; g < 4; ++g) {
      f32x4 cr = MFMA(a0, Whh[g  ][0], zero); cr = MFMA(a1, Whh[g  ][1], cr);
      f32x4 cz = MFMA(a0, Whh[g+4][0], zero); cz = MFMA(a1, Whh[g+4][1], cz);
      const f32x4 cninit = {bhn[g], bhn[g], bhn[g], bhn[g]};
      f32x4 cn = MFMA(a0, Whh[g+8][0], cninit); cn = MFMA(a1, Whh[g+8][1], cn);
      const float4 Tr = gi_tab[      g*16 + n16];
      const float4 Tz = gi_tab[ 64 + g*16 + n16];
      const float4 Tn = gi_tab[128 + g*16 + n16];
      #pragma unroll
      for (int i = 0; i < 4; ++i) {
        const float gir = fmaf(Tr.x, ys0[i], fmaf(Tr.y, ys1[i], Tr.z));
        const float giz = fmaf(Tz.x, ys0[i], fmaf(Tz.y, ys1[i], Tz.z));
        const float gin = fmaf(Tn.x, ys0[i], fmaf(Tn.y, ys1[i], Tn.z));
        const float r  = sigm(gir + cr[i]);
        const float u  = sigm(giz + cz[i]);
        const float nn = tanh_f(fmaf(r, cn[i], gin));
        const float hv = fmaf(u, hst[g][i] - nn, nn);
        hst[g][i] = hv;
        hbuf[(wave*16 + quad*4 + i)*72 + g*16 + n16] = (__bf16)hv;
      }
    }

    // new-h A-frags (reused by MLP1 and carried into next t)
    a0 = *(const bf16x8*)&hbuf[arow*72 + quad*8];
    a1 = *(const bf16x8*)&hbuf[arow*72 + 32 + quad*8];

    // ---- MLP1: hid = relu(h@W1 + b1), bias via C-init ----
    #pragma unroll
    for (int c2 = 0; c2 < 2; ++c2) {
      const float bb = c2 ? b1v1 : b1v0;
      const f32x4 binit = {bb, bb, bb, bb};
      f32x4 hc = MFMA(a0, *(const bf16x8*)&w1tab[((c2*2  )*64 + lane)*8], binit);
      hc       = MFMA(a1, *(const bf16x8*)&w1tab[((c2*2+1)*64 + lane)*8], hc);
      #pragma unroll
      for (int i = 0; i < 4; ++i)
        hidbuf[(wave*16 + quad*4 + i)*40 + c2*16 + n16] = (__bf16)fmaxf(hc[i], 0.f);
    }

    // ---- MLP2: ls = hid@W2 + b2 (C-init) ----
    {
      const bf16x8 ha = *(const bf16x8*)&hidbuf[arow*40 + quad*8];
      const f32x4 b2init = {b2ln, b2ln, b2ln, b2ln};
      const f32x4 ls = MFMA(ha, *(const bf16x8*)&w2tab[lane*8], b2init);
      if (n16 < 4) {
        #pragma unroll
        for (int i = 0; i < 4; ++i)
          lsbuf[(wave*16 + quad*4 + i)*4 + n16] = ls[i];
      }
    }

    // ---- epilogue, 32 lanes (comp-parallel) ----
    if (lane < 32) {
      const float lc = lsbuf[erow*4 + comp];
      const float l2 = lsbuf[erow*4 + 2 + comp];
      const float s  = __logf(1.0f + __expf(l2)) + 0.001f;
      const float xt = xp[t*2];
      yc += lc + s * xt;
      lad += __logf(s);
      ystate[erow*2 + comp] = yc;
      ybuf[erow*34 + t*2 + comp] = yc;
    }
  }

  // ---- lad: combine the two comps ----
  const float lado = __shfl(lad, lane ^ 16, 64);
  if (lane < 16) lad_out[gb + wave*16 + lane] = lad + lado;

  // ---- coalesced y flush ----
  #pragma unroll
  for (int it = 0; it < 4; ++it) {
    const int n = it*64 + lane;           // 256 float2 per wave strip
    const int row = n >> 4, tt = n & 15;
    float2 v;
    v.x = ybuf[(wave*16 + row)*34 + tt*2];
    v.y = ybuf[(wave*16 + row)*34 + tt*2 + 1];
    *(float2*)&y_out[(size_t)(gb + wave*16 + row)*32 + tt*2] = v;
  }
}

extern "C" void kernel_launch(void* const* d_in, const int* in_sizes, int n_in,
                              void* d_out, int out_size, void* d_ws, size_t ws_size,
                              hipStream_t stream) {
  const float* x    = (const float*)d_in[0];
  const float* z    = (const float*)d_in[1];
  const float* W_ih = (const float*)d_in[2];
  const float* W_hh = (const float*)d_in[3];
  const float* b_ih = (const float*)d_in[4];
  const float* b_hh = (const float*)d_in[5];
  const float* W1   = (const float*)d_in[6];
  const float* b1   = (const float*)d_in[7];
  const float* W2   = (const float*)d_in[8];
  const float* b2   = (const float*)d_in[9];

  float* y_out   = (float*)d_out;
  float* lad_out = y_out + (size_t)BSZ * TT * 2;

  dim3 grid(BSZ / RPB), block(BLK);
  hipLaunchKernelGGL(flow3, grid, block, 0, stream,
                     x, z, W_ih, W_hh, b_ih, b_hh, W1, b1, W2, b2,
                     y_out, lad_out);
}

// Round 4
// 362.282 us; speedup vs baseline: 1.4708x; 1.4708x over previous
//
#include <hip/hip_runtime.h>

// B=131072, T=16, D=2, H=64. 16 rows/wave, 4 waves/block.
// R4: Whh r-gate frags in regs (32 VGPR), z/n-gate frags in LDS (shared/block);
// no ybuf (direct global y stores). Target: VGPR<=128 AND LDS<=40KB -> 16 waves/CU.
#define BSZ 131072
#define TT  16
#define RPB 64
#define BLK 256

typedef __bf16 bf16x8 __attribute__((ext_vector_type(8)));
typedef float  f32x4  __attribute__((ext_vector_type(4)));

#define MFMA(a,b,c) __builtin_amdgcn_mfma_f32_16x16x32_bf16((a),(b),(c),0,0,0)

static __device__ __forceinline__ float rcp_f(float v){ float r; asm("v_rcp_f32 %0, %1" : "=v"(r) : "v"(v)); return r; }
static __device__ __forceinline__ float sigm(float v){ return rcp_f(1.0f + __expf(-v)); }
static __device__ __forceinline__ float tanh_f(float v){ return 1.0f - 2.0f*rcp_f(1.0f + __expf(2.0f*v)); }

__global__ __launch_bounds__(BLK, 4) void flow4(
    const float* __restrict__ x,     // (B,16,2)
    const float* __restrict__ z,     // (B,64)
    const float* __restrict__ W_ih,  // (192,2)
    const float* __restrict__ W_hh,  // (192,64)
    const float* __restrict__ b_ih,  // (192)
    const float* __restrict__ b_hh,  // (192)
    const float* __restrict__ W1,    // (64,32)
    const float* __restrict__ b1,    // (32)
    const float* __restrict__ W2,    // (32,4)
    const float* __restrict__ b2,    // (4)
    float* __restrict__ y_out,       // (B,16,2)
    float* __restrict__ lad_out)     // (B)
{
  // ---- LDS budget: 16384+4096+1024+3072+9216+5120+1024+512 = 40448 B (<=40960 -> 4 blk/CU)
  __shared__ __align__(16) __bf16 whhtab[16*64*8];  // z/n-gate B-frags [f][lane][8]
  __shared__ __align__(16) __bf16 w1tab[4*64*8];    // W1 B-frags
  __shared__ __align__(16) __bf16 w2tab[64*8];      // W2 B-frag
  __shared__ __align__(16) float4 gi_tab[192];      // {Wih0, Wih1, bias, 0}
  __shared__ __align__(16) __bf16 hbuf[RPB*72];     // h bf16, stride 72
  __shared__ __align__(16) __bf16 hidbuf[RPB*40];   // MLP hidden, stride 40
  __shared__ __align__(16) float  lsbuf[RPB*4];
  __shared__ __align__(16) float  ystate[RPB*2];    // y_{t-1} [row][comp]

  const int tid  = threadIdx.x;
  const int lane = tid & 63, wave = tid >> 6;
  const int quad = lane >> 4, n16 = lane & 15;
  const int gb   = blockIdx.x * RPB;
  const f32x4 zero = {0.f,0.f,0.f,0.f};

  // ---------- one-time staging ----------
  if (tid < 192) {
    const int j = tid;
    const float w0 = W_ih[2*j], w1 = W_ih[2*j+1];
    const float bi = b_ih[j], bh = b_hh[j];
    gi_tab[j] = make_float4(w0, w1, (j < 128) ? bi + bh : bi, 0.f);
  }
  // whhtab: 16 frags (f = (gate-1)*8 + g*2 + kt, gate 1=z 2=n); each wave stages 4
  #pragma unroll
  for (int i = 0; i < 4; ++i) {
    const int f = i*4 + wave;
    const int gate = 1 + (f >> 3), g = (f >> 1) & 3, kt = f & 1;
    const float* p = W_hh + (size_t)((gate*4 + g)*16 + n16)*64 + kt*32 + quad*8;
    bf16x8 v;
    #pragma unroll
    for (int j = 0; j < 8; ++j) v[j] = (__bf16)p[j];
    *(bf16x8*)&whhtab[(f*64 + lane)*8] = v;
  }
  { // w1tab: frag f = c2*2+kt, one per wave
    const int f = wave, c2 = f >> 1, kt = f & 1;
    bf16x8 v;
    #pragma unroll
    for (int j = 0; j < 8; ++j)
      v[j] = (__bf16)W1[(size_t)(kt*32 + quad*8 + j)*32 + c2*16 + n16];
    *(bf16x8*)&w1tab[(f*64 + lane)*8] = v;
  }
  if (tid < 64) {
    bf16x8 v;
    #pragma unroll
    for (int j = 0; j < 8; ++j)
      v[j] = (n16 < 4) ? (__bf16)W2[(size_t)(quad*8 + j)*4 + n16] : (__bf16)0.f;
    *(bf16x8*)&w2tab[lane*8] = v;
  }
  if (tid < 128) ystate[tid] = 0.f;
  #pragma unroll
  for (int r4 = 0; r4 < 4; ++r4) {  // z -> hbuf (bf16)
    const int row = (tid >> 4) + r4*16, col = (tid & 15)*4;
    const float4 zv = *(const float4*)&z[(size_t)(gb + row)*64 + col];
    hbuf[row*72 + col+0] = (__bf16)zv.x; hbuf[row*72 + col+1] = (__bf16)zv.y;
    hbuf[row*72 + col+2] = (__bf16)zv.z; hbuf[row*72 + col+3] = (__bf16)zv.w;
  }

  // r-gate B-frags in registers: 8 x bf16x8 = 32 VGPR
  bf16x8 Whr[4][2];
  #pragma unroll
  for (int g = 0; g < 4; ++g)
    #pragma unroll
    for (int kt = 0; kt < 2; ++kt) {
      const float* p = W_hh + (size_t)(g*16 + n16)*64 + kt*32 + quad*8;
      bf16x8 v;
      #pragma unroll
      for (int j = 0; j < 8; ++j) v[j] = (__bf16)p[j];
      Whr[g][kt] = v;
    }
  // h state fp32 C-layout: hst[g][i] = h[quad*4+i][g*16+n16]
  f32x4 hst[4];
  #pragma unroll
  for (int g = 0; g < 4; ++g)
    #pragma unroll
    for (int i = 0; i < 4; ++i)
      hst[g][i] = z[(size_t)(gb + wave*16 + quad*4 + i)*64 + g*16 + n16];
  float bhn[4];
  #pragma unroll
  for (int g = 0; g < 4; ++g) bhn[g] = b_hh[128 + g*16 + n16];
  const float b1v0 = b1[n16], b1v1 = b1[16 + n16];
  const float b2ln = (n16 < 4) ? b2[n16] : 0.f;

  __syncthreads();  // only barrier; t-loop LDS is wave-private rows + RO tables

  const int arow = wave*16 + n16;
  bf16x8 a0 = *(const bf16x8*)&hbuf[arow*72 + quad*8];
  bf16x8 a1 = *(const bf16x8*)&hbuf[arow*72 + 32 + quad*8];

  // epilogue: 32 lanes, comp = lane>>4, row = lane&15
  const int erow = wave*16 + (lane & 15);
  const int comp = (lane >> 4) & 1;
  const float* xp = x + (size_t)(gb + erow)*(TT*2) + comp;
  float*       yp = y_out + (size_t)(gb + erow)*(TT*2) + comp;
  float yc = 0.f, lad = 0.f;

  #pragma unroll 1
  for (int t = 0; t < TT; ++t) {
    float ys0[4], ys1[4];
    #pragma unroll
    for (int i = 0; i < 4; ++i) {
      const float2 yv = *(const float2*)&ystate[(wave*16 + quad*4 + i)*2];
      ys0[i] = yv.x; ys1[i] = yv.y;
    }

    // ---- GRU per col-group g ----
    #pragma unroll
    for (int g = 0; g < 4; ++g) {
      const bf16x8 bz0 = *(const bf16x8*)&whhtab[((g*2    )*64 + lane)*8];
      const bf16x8 bz1 = *(const bf16x8*)&whhtab[((g*2 + 1)*64 + lane)*8];
      const bf16x8 bn0 = *(const bf16x8*)&whhtab[((8 + g*2    )*64 + lane)*8];
      const bf16x8 bn1 = *(const bf16x8*)&whhtab[((8 + g*2 + 1)*64 + lane)*8];
      f32x4 cr = MFMA(a0, Whr[g][0], zero); cr = MFMA(a1, Whr[g][1], cr);
      f32x4 cz = MFMA(a0, bz0, zero);       cz = MFMA(a1, bz1, cz);
      const f32x4 cninit = {bhn[g], bhn[g], bhn[g], bhn[g]};
      f32x4 cn = MFMA(a0, bn0, cninit);     cn = MFMA(a1, bn1, cn);
      const float4 Tr = gi_tab[      g*16 + n16];
      const float4 Tz = gi_tab[ 64 + g*16 + n16];
      const float4 Tn = gi_tab[128 + g*16 + n16];
      #pragma unroll
      for (int i = 0; i < 4; ++i) {
        const float gir = fmaf(Tr.x, ys0[i], fmaf(Tr.y, ys1[i], Tr.z));
        const float giz = fmaf(Tz.x, ys0[i], fmaf(Tz.y, ys1[i], Tz.z));
        const float gin = fmaf(Tn.x, ys0[i], fmaf(Tn.y, ys1[i], Tn.z));
        const float r  = sigm(gir + cr[i]);
        const float u  = sigm(giz + cz[i]);
        const float nn = tanh_f(fmaf(r, cn[i], gin));
        const float hv = fmaf(u, hst[g][i] - nn, nn);
        hst[g][i] = hv;
        hbuf[(wave*16 + quad*4 + i)*72 + g*16 + n16] = (__bf16)hv;
      }
    }

    a0 = *(const bf16x8*)&hbuf[arow*72 + quad*8];
    a1 = *(const bf16x8*)&hbuf[arow*72 + 32 + quad*8];

    // ---- MLP1 ----
    #pragma unroll
    for (int c2 = 0; c2 < 2; ++c2) {
      const float bb = c2 ? b1v1 : b1v0;
      const f32x4 binit = {bb, bb, bb, bb};
      f32x4 hc = MFMA(a0, *(const bf16x8*)&w1tab[((c2*2  )*64 + lane)*8], binit);
      hc       = MFMA(a1, *(const bf16x8*)&w1tab[((c2*2+1)*64 + lane)*8], hc);
      #pragma unroll
      for (int i = 0; i < 4; ++i)
        hidbuf[(wave*16 + quad*4 + i)*40 + c2*16 + n16] = (__bf16)fmaxf(hc[i], 0.f);
    }

    // ---- MLP2 ----
    {
      const bf16x8 ha = *(const bf16x8*)&hidbuf[arow*40 + quad*8];
      const f32x4 b2init = {b2ln, b2ln, b2ln, b2ln};
      const f32x4 ls = MFMA(ha, *(const bf16x8*)&w2tab[lane*8], b2init);
      if (n16 < 4) {
        #pragma unroll
        for (int i = 0; i < 4; ++i)
          lsbuf[(wave*16 + quad*4 + i)*4 + n16] = ls[i];
      }
    }

    // ---- epilogue (32 lanes, comp-parallel), direct global y store ----
    if (lane < 32) {
      const float lc = lsbuf[erow*4 + comp];
      const float l2 = lsbuf[erow*4 + 2 + comp];
      const float s  = __logf(1.0f + __expf(l2)) + 0.001f;
      const float xt = xp[t*2];
      yc += lc + s * xt;
      lad += __logf(s);
      ystate[erow*2 + comp] = yc;
      yp[t*2] = yc;
    }
  }

  const float lado = __shfl(lad, lane ^ 16, 64);
  if (lane < 16) lad_out[gb + wave*16 + lane] = lad + lado;
}

extern "C" void kernel_launch(void* const* d_in, const int* in_sizes, int n_in,
                              void* d_out, int out_size, void* d_ws, size_t ws_size,
                              hipStream_t stream) {
  const float* x    = (const float*)d_in[0];
  const float* z    = (const float*)d_in[1];
  const float* W_ih = (const float*)d_in[2];
  const float* W_hh = (const float*)d_in[3];
  const float* b_ih = (const float*)d_in[4];
  const float* b_hh = (const float*)d_in[5];
  const float* W1   = (const float*)d_in[6];
  const float* b1   = (const float*)d_in[7];
  const float* W2   = (const float*)d_in[8];
  const float* b2   = (const float*)d_in[9];

  float* y_out   = (float*)d_out;
  float* lad_out = y_out + (size_t)BSZ * TT * 2;

  dim3 grid(BSZ / RPB), block(BLK);
  hipLaunchKernelGGL(flow4, grid, block, 0, stream,
                     x, z, W_ih, W_hh, b_ih, b_hh, W1, b1, W2, b2,
                     y_out, lad_out);
}

// Round 5
// 244.246 us; speedup vs baseline: 2.1816x; 1.4833x over previous
//
#include <hip/hip_runtime.h>

// B=131072, T=16, D=2, H=64. 16 rows/wave, 4 waves/block.
// R5: Whr in regs (32 VGPR), z/n + W1 frags in LDS; lsbuf folded into hidbuf pad;
// gate weights pre-scaled by -log2e (r,z) / +2log2e (n) -> exp2-form gates.
// bounds(256,3): cap ~170 vs ~120 live -> no spill, 12 waves/CU.
#define BSZ 131072
#define TT  16
#define RPB 64
#define BLK 256

#define LOG2E      1.4426950408889634f
#define NEG_LOG2E  (-1.4426950408889634f)
#define TWO_LOG2E  2.8853900817779268f

typedef __bf16 bf16x8 __attribute__((ext_vector_type(8)));
typedef float  f32x4  __attribute__((ext_vector_type(4)));

#define MFMA(a,b,c) __builtin_amdgcn_mfma_f32_16x16x32_bf16((a),(b),(c),0,0,0)

static __device__ __forceinline__ float rcp_f(float v){ float r; asm("v_rcp_f32 %0, %1" : "=v"(r) : "v"(v)); return r; }
static __device__ __forceinline__ float exp2_f(float v){ float r; asm("v_exp_f32 %0, %1" : "=v"(r) : "v"(v)); return r; }

__global__ __launch_bounds__(BLK, 3) void flow5(
    const float* __restrict__ x,     // (B,16,2)
    const float* __restrict__ z,     // (B,64)
    const float* __restrict__ W_ih,  // (192,2)
    const float* __restrict__ W_hh,  // (192,64)
    const float* __restrict__ b_ih,  // (192)
    const float* __restrict__ b_hh,  // (192)
    const float* __restrict__ W1,    // (64,32)
    const float* __restrict__ b1,    // (32)
    const float* __restrict__ W2,    // (32,4)
    const float* __restrict__ b2,    // (4)
    float* __restrict__ y_out,       // (B,16,2)
    float* __restrict__ lad_out)     // (B)
{
  // LDS: 16384 + 4096 + 3072 + 9216 + 5120 + 512 = 38400 B
  __shared__ __align__(16) __bf16 whhtab[16*64*8];  // z/n-gate B-frags [f][lane][8] (pre-scaled)
  __shared__ __align__(16) __bf16 w1tab[4*64*8];    // W1 B-frags
  __shared__ __align__(16) float4 gi_tab[192];      // {Wih0, Wih1, bias, 0} (pre-scaled)
  __shared__ __align__(16) __bf16 hbuf[RPB*72];     // h bf16, stride 72; cols 64..71 pad
  __shared__ __align__(16) __bf16 hidbuf[RPB*40];   // hidden, stride 40; cols 32..39 = ls pad
  __shared__ __align__(16) float  ystate[RPB*2];    // y_{t-1} [row][comp]

  const int tid  = threadIdx.x;
  const int lane = tid & 63, wave = tid >> 6;
  const int quad = lane >> 4, n16 = lane & 15;
  const int gb   = blockIdx.x * RPB;
  const f32x4 zero = {0.f,0.f,0.f,0.f};

  // ---------- one-time staging ----------
  if (tid < 192) {  // gi_tab, pre-scaled
    const int j = tid;
    const float sc = (j < 128) ? NEG_LOG2E : TWO_LOG2E;
    const float w0 = W_ih[2*j]*sc, w1 = W_ih[2*j+1]*sc;
    const float bi = b_ih[j], bh = b_hh[j];
    gi_tab[j] = make_float4(w0, w1, ((j < 128) ? bi + bh : bi)*sc, 0.f);
  }
  // whhtab: f = (gate-1)*8 + g*2 + kt, gate 1=z (x -log2e), 2=n (x 2log2e)
  #pragma unroll
  for (int i = 0; i < 4; ++i) {
    const int f = i*4 + wave;
    const int gate = 1 + (f >> 3), g = (f >> 1) & 3, kt = f & 1;
    const float sc = (gate == 1) ? NEG_LOG2E : TWO_LOG2E;
    const float* p = W_hh + (size_t)((gate*4 + g)*16 + n16)*64 + kt*32 + quad*8;
    bf16x8 v;
    #pragma unroll
    for (int j = 0; j < 8; ++j) v[j] = (__bf16)(p[j]*sc);
    *(bf16x8*)&whhtab[(f*64 + lane)*8] = v;
  }
  { // w1tab: frag f = c2*2+kt, one per wave (unscaled)
    const int f = wave, c2 = f >> 1, kt = f & 1;
    bf16x8 v;
    #pragma unroll
    for (int j = 0; j < 8; ++j)
      v[j] = (__bf16)W1[(size_t)(kt*32 + quad*8 + j)*32 + c2*16 + n16];
    *(bf16x8*)&w1tab[(f*64 + lane)*8] = v;
  }
  if (tid < 128) ystate[tid] = 0.f;
  #pragma unroll
  for (int r4 = 0; r4 < 4; ++r4) {  // z -> hbuf (bf16)
    const int row = (tid >> 4) + r4*16, col = (tid & 15)*4;
    const float4 zv = *(const float4*)&z[(size_t)(gb + row)*64 + col];
    hbuf[row*72 + col+0] = (__bf16)zv.x; hbuf[row*72 + col+1] = (__bf16)zv.y;
    hbuf[row*72 + col+2] = (__bf16)zv.z; hbuf[row*72 + col+3] = (__bf16)zv.w;
  }

  // r-gate B-frags in regs (pre-scaled by -log2e): 8 x bf16x8 = 32 VGPR
  bf16x8 Whr[4][2];
  #pragma unroll
  for (int g = 0; g < 4; ++g)
    #pragma unroll
    for (int kt = 0; kt < 2; ++kt) {
      const float* p = W_hh + (size_t)(g*16 + n16)*64 + kt*32 + quad*8;
      bf16x8 v;
      #pragma unroll
      for (int j = 0; j < 8; ++j) v[j] = (__bf16)(p[j]*NEG_LOG2E);
      Whr[g][kt] = v;
    }
  // W2 B-frag in regs (4 VGPR)
  bf16x8 W2f;
  #pragma unroll
  for (int j = 0; j < 8; ++j)
    W2f[j] = (n16 < 4) ? (__bf16)W2[(size_t)(quad*8 + j)*4 + n16] : (__bf16)0.f;

  // h state fp32 C-layout: hst[g][i] = h[quad*4+i][g*16+n16]
  f32x4 hst[4];
  #pragma unroll
  for (int g = 0; g < 4; ++g)
    #pragma unroll
    for (int i = 0; i < 4; ++i)
      hst[g][i] = z[(size_t)(gb + wave*16 + quad*4 + i)*64 + g*16 + n16];
  float bhn[4];   // b_hh n-part, scaled (folded into cn C-init)
  #pragma unroll
  for (int g = 0; g < 4; ++g) bhn[g] = b_hh[128 + g*16 + n16]*TWO_LOG2E;
  const float b1v0 = b1[n16], b1v1 = b1[16 + n16];
  const float b2ln = (n16 < 4) ? b2[n16] : 0.f;

  __syncthreads();  // only barrier

  const int arow = wave*16 + n16;
  bf16x8 a0 = *(const bf16x8*)&hbuf[arow*72 + quad*8];
  bf16x8 a1 = *(const bf16x8*)&hbuf[arow*72 + 32 + quad*8];

  // epilogue: 32 lanes, comp = lane>>4, row = lane&15
  const int erow = wave*16 + (lane & 15);
  const int comp = (lane >> 4) & 1;
  const float* xp = x + (size_t)(gb + erow)*(TT*2) + comp;
  float*       yp = y_out + (size_t)(gb + erow)*(TT*2) + comp;
  float yc = 0.f, lad = 0.f;

  #pragma unroll 1
  for (int t = 0; t < TT; ++t) {
    const float xt = (lane < 32) ? xp[t*2] : 0.f;   // issue global load early
    float ys0[4], ys1[4];
    #pragma unroll
    for (int i = 0; i < 4; ++i) {
      const float2 yv = *(const float2*)&ystate[(wave*16 + quad*4 + i)*2];
      ys0[i] = yv.x; ys1[i] = yv.y;
    }

    // ---- GRU per col-group g (all pre-activations in scaled domain) ----
    #pragma unroll
    for (int g = 0; g < 4; ++g) {
      const bf16x8 bz0 = *(const bf16x8*)&whhtab[((g*2    )*64 + lane)*8];
      const bf16x8 bz1 = *(const bf16x8*)&whhtab[((g*2 + 1)*64 + lane)*8];
      const bf16x8 bn0 = *(const bf16x8*)&whhtab[((8 + g*2    )*64 + lane)*8];
      const bf16x8 bn1 = *(const bf16x8*)&whhtab[((8 + g*2 + 1)*64 + lane)*8];
      f32x4 cr = MFMA(a0, Whr[g][0], zero); cr = MFMA(a1, Whr[g][1], cr);
      f32x4 cz = MFMA(a0, bz0, zero);       cz = MFMA(a1, bz1, cz);
      const f32x4 cninit = {bhn[g], bhn[g], bhn[g], bhn[g]};
      f32x4 cn = MFMA(a0, bn0, cninit);     cn = MFMA(a1, bn1, cn);
      const float4 Tr = gi_tab[      g*16 + n16];
      const float4 Tz = gi_tab[ 64 + g*16 + n16];
      const float4 Tn = gi_tab[128 + g*16 + n16];
      #pragma unroll
      for (int i = 0; i < 4; ++i) {
        const float sr = fmaf(Tr.x, ys0[i], fmaf(Tr.y, ys1[i], Tr.z)) + cr[i]; // = -log2e*vr
        const float sz = fmaf(Tz.x, ys0[i], fmaf(Tz.y, ys1[i], Tz.z)) + cz[i]; // = -log2e*vz
        const float gin = fmaf(Tn.x, ys0[i], fmaf(Tn.y, ys1[i], Tn.z));        // = 2log2e*(..)
        const float r  = rcp_f(1.0f + exp2_f(sr));
        const float u  = rcp_f(1.0f + exp2_f(sz));
        const float pre = fmaf(r, cn[i], gin);                                 // = 2log2e*vn
        const float nn = fmaf(-2.0f, rcp_f(1.0f + exp2_f(pre)), 1.0f);         // tanh(vn)
        const float hv = fmaf(u, hst[g][i] - nn, nn);
        hst[g][i] = hv;
        hbuf[(wave*16 + quad*4 + i)*72 + g*16 + n16] = (__bf16)hv;
      }
    }

    a0 = *(const bf16x8*)&hbuf[arow*72 + quad*8];
    a1 = *(const bf16x8*)&hbuf[arow*72 + 32 + quad*8];

    // ---- MLP1 ----
    #pragma unroll
    for (int c2 = 0; c2 < 2; ++c2) {
      const float bb = c2 ? b1v1 : b1v0;
      const f32x4 binit = {bb, bb, bb, bb};
      f32x4 hc = MFMA(a0, *(const bf16x8*)&w1tab[((c2*2  )*64 + lane)*8], binit);
      hc       = MFMA(a1, *(const bf16x8*)&w1tab[((c2*2+1)*64 + lane)*8], hc);
      #pragma unroll
      for (int i = 0; i < 4; ++i)
        hidbuf[(wave*16 + quad*4 + i)*40 + c2*16 + n16] = (__bf16)fmaxf(hc[i], 0.f);
    }

    // ---- MLP2: ls -> hidbuf pad (cols 32..39 as 4 floats) ----
    {
      const bf16x8 ha = *(const bf16x8*)&hidbuf[arow*40 + quad*8];
      const f32x4 b2init = {b2ln, b2ln, b2ln, b2ln};
      const f32x4 ls = MFMA(ha, W2f, b2init);
      if (n16 < 4) {
        #pragma unroll
        for (int i = 0; i < 4; ++i)
          ((float*)&hidbuf[(wave*16 + quad*4 + i)*40 + 32])[n16] = ls[i];
      }
    }

    // ---- epilogue (32 lanes), direct global y store ----
    if (lane < 32) {
      const float* lsp = (const float*)&hidbuf[erow*40 + 32];
      const float lc = lsp[comp];
      const float l2 = lsp[2 + comp];
      const float s  = __logf(1.0f + __expf(l2)) + 0.001f;
      yc += lc + s * xt;
      lad += __logf(s);
      ystate[erow*2 + comp] = yc;
      yp[t*2] = yc;
    }
  }

  const float lado = __shfl(lad, lane ^ 16, 64);
  if (lane < 16) lad_out[gb + wave*16 + lane] = lad + lado;
}

extern "C" void kernel_launch(void* const* d_in, const int* in_sizes, int n_in,
                              void* d_out, int out_size, void* d_ws, size_t ws_size,
                              hipStream_t stream) {
  const float* x    = (const float*)d_in[0];
  const float* z    = (const float*)d_in[1];
  const float* W_ih = (const float*)d_in[2];
  const float* W_hh = (const float*)d_in[3];
  const float* b_ih = (const float*)d_in[4];
  const float* b_hh = (const float*)d_in[5];
  const float* W1   = (const float*)d_in[6];
  const float* b1   = (const float*)d_in[7];
  const float* W2   = (const float*)d_in[8];
  const float* b2   = (const float*)d_in[9];

  float* y_out   = (float*)d_out;
  float* lad_out = y_out + (size_t)BSZ * TT * 2;

  dim3 grid(BSZ / RPB), block(BLK);
  hipLaunchKernelGGL(flow5, grid, block, 0, stream,
                     x, z, W_ih, W_hh, b_ih, b_hh, W1, b1, W2, b2,
                     y_out, lad_out);
}